// Round 5
// baseline (679.830 us; speedup 1.0000x reference)
//
#include <hip/hip_runtime.h>

#define E_TOTAL   500000
#define NN        50000
#define ND        128
#define ED        128
#define HID       256
#define IND       384   /* 2*ND + ED */
#define EB        64
#define NBLOCKS   ((E_TOTAL + EB - 1) / EB)

typedef float  f32x4  __attribute__((ext_vector_type(4)));
typedef short  bf16x8 __attribute__((ext_vector_type(8)));

__device__ __forceinline__ unsigned short f2bf(float f) {
    unsigned int u = __float_as_uint(f);
    u += 0x7FFFu + ((u >> 16) & 1u);   // RNE
    return (unsigned short)(u >> 16);
}
__device__ __forceinline__ float bf2f(unsigned short h) {
    return __uint_as_float(((unsigned int)h) << 16);
}

// ---------------- prep: weights fp32 -> bf16 transposed ----------------
__global__ void prep_w1(const float* __restrict__ w1, unsigned short* __restrict__ w1t) {
    int i = blockIdx.x * blockDim.x + threadIdx.x;
    if (i >= IND * HID) return;
    int k = i / HID, n = i % HID;
    w1t[n * IND + k] = f2bf(w1[i]);       // W1T[n][k] = W1[k][n]
}

__global__ void prep_w2(const float* __restrict__ w2, unsigned short* __restrict__ w2t) {
    int i = blockIdx.x * blockDim.x + threadIdx.x;
    if (i >= HID * ED) return;
    int k = i / ED, n = i % ED;
    w2t[n * HID + k] = f2bf(w2[i]);       // W2T[n][k] = W2[k][n]
}

// ---------------- prep: per-node partial products ----------------
// Psrc[n][:] = nodes[n] @ W1[0:128, :] + b1   (bf16, 50000x256)
// Pdst[n][:] = nodes[n] @ W1[128:256, :]      (bf16, 50000x256)
__global__ __launch_bounds__(256, 2)
void prep_ptab(const float* __restrict__ nf,
               const unsigned short* __restrict__ w1t,
               const float* __restrict__ b1,
               unsigned short* __restrict__ Psrc,
               unsigned short* __restrict__ Pdst) {
    __shared__ unsigned short An[EB * ND];   // 16 KB swizzled
    const int tid  = threadIdx.x;
    const int base = blockIdx.x * EB;
    const int lane = tid & 63;
    const int w    = tid >> 6;
    const int l15  = lane & 15;
    const int lhi  = lane >> 4;

    #pragma unroll
    for (int it = 0; it < 4; ++it) {
        int item = tid + it * 256;          // 0..1023
        int row = item >> 4, cc = item & 15;
        int nidx = base + row;
        if (nidx >= NN) nidx = NN - 1;
        const float* p = nf + (size_t)nidx * ND + cc * 8;
        float4 f0 = *(const float4*)p;
        float4 f1 = *(const float4*)(p + 4);
        bf16x8 val;
        val[0] = (short)f2bf(f0.x); val[1] = (short)f2bf(f0.y);
        val[2] = (short)f2bf(f0.z); val[3] = (short)f2bf(f0.w);
        val[4] = (short)f2bf(f1.x); val[5] = (short)f2bf(f1.y);
        val[6] = (short)f2bf(f1.z); val[7] = (short)f2bf(f1.w);
        *(bf16x8*)(An + row * ND + ((cc * 8) ^ ((row & 7) * 8))) = val;
    }
    __syncthreads();

    f32x4 accs[4][4], accd[4][4];
    #pragma unroll
    for (int mt = 0; mt < 4; ++mt)
        #pragma unroll
        for (int nt = 0; nt < 4; ++nt) { accs[mt][nt] = (f32x4)0.0f; accd[mt][nt] = (f32x4)0.0f; }

    #pragma unroll
    for (int ks = 0; ks < 4; ++ks) {
        int c0 = ks * 32 + lhi * 8;
        bf16x8 a[4];
        #pragma unroll
        for (int mt = 0; mt < 4; ++mt) {
            int row = mt * 16 + l15;
            a[mt] = *(const bf16x8*)(An + row * ND + (c0 ^ ((row & 7) * 8)));
        }
        #pragma unroll
        for (int nt = 0; nt < 4; ++nt) {
            int n = w * 64 + nt * 16 + l15;
            bf16x8 bs = *(const bf16x8*)(w1t + (size_t)n * IND + c0);         // W1 rows 0:128
            bf16x8 bd = *(const bf16x8*)(w1t + (size_t)n * IND + 128 + c0);   // W1 rows 128:256
            #pragma unroll
            for (int mt = 0; mt < 4; ++mt) {
                accs[mt][nt] = __builtin_amdgcn_mfma_f32_16x16x32_bf16(a[mt], bs, accs[mt][nt], 0, 0, 0);
                accd[mt][nt] = __builtin_amdgcn_mfma_f32_16x16x32_bf16(a[mt], bd, accd[mt][nt], 0, 0, 0);
            }
        }
    }

    #pragma unroll
    for (int nt = 0; nt < 4; ++nt) {
        int col = w * 64 + nt * 16 + l15;
        float bias = b1[col];
        #pragma unroll
        for (int mt = 0; mt < 4; ++mt) {
            #pragma unroll
            for (int r = 0; r < 4; ++r) {
                int row = mt * 16 + lhi * 4 + r;
                int nidx = base + row;
                if (nidx < NN) {
                    size_t off = (size_t)nidx * HID + col;
                    Psrc[off] = f2bf(accs[mt][nt][r] + bias);
                    Pdst[off] = f2bf(accd[mt][nt][r]);
                }
            }
        }
    }
}

// ---------------- main fused kernel ----------------
// LDS = Hs[64][256] bf16 swizzled ONLY (32 KB) -> 5 blocks/CU.
// GEMM1 A-fragments load straight from global edgef (f32->bf16 in regs);
// residual re-reads edgef (L1/L2-hot). Phases:
//   gather Hs = Psrc[src]+Pdst[dst]  (no barrier yet)
//   GEMM1 (doesn't touch Hs; other waves' gathers overlap it)
//   barrier; merge relu(acc1+Hs)->Hs; barrier
//   GEMM2; epilogue out = edgef + update + b2
__global__ __launch_bounds__(256, 5)
void edge_mlp(const float* __restrict__ edgef,
              const int* __restrict__ eidx,
              const unsigned short* __restrict__ Psrc,
              const unsigned short* __restrict__ Pdst,
              const unsigned short* __restrict__ w1t,
              const unsigned short* __restrict__ w2t,
              const float* __restrict__ b2,
              float* __restrict__ out) {
    __shared__ unsigned short Hs[EB * HID];   // 32 KB

    const int tid  = threadIdx.x;
    const int base = blockIdx.x * EB;
    const int lane = tid & 63;
    const int w    = tid >> 6;
    const int l15  = lane & 15;
    const int lhi  = lane >> 4;
    const int* srcI = eidx;
    const int* dstI = eidx + E_TOTAL;

    // ---- gather: Hs[row][:] = Psrc[src[row]][:] + Pdst[dst[row]][:] ----
    #pragma unroll
    for (int it = 0; it < 8; ++it) {
        int item = tid + it * 256;           // 0..2047 = 64 rows x 32 chunks
        int row = item >> 5, cc = item & 31;
        int e = base + row;
        int el = e < E_TOTAL ? e : E_TOTAL - 1;
        int s = srcI[el], d = dstI[el];
        bf16x8 vs = *(const bf16x8*)(Psrc + (size_t)s * HID + cc * 8);
        bf16x8 vd = *(const bf16x8*)(Pdst + (size_t)d * HID + cc * 8);
        bf16x8 o;
        #pragma unroll
        for (int j = 0; j < 8; ++j)
            o[j] = (short)f2bf(bf2f((unsigned short)vs[j]) + bf2f((unsigned short)vd[j]));
        *(bf16x8*)(Hs + row * HID + ((cc * 8) ^ ((row & 7) * 8))) = o;
    }

    // ---- GEMM1: acc1(64x256) = edge(64x128) @ W1[256:384,:] ----
    // A-fragments straight from global (f32 -> bf16); no LDS, no barrier.
    const float* pA[4];
    #pragma unroll
    for (int mt = 0; mt < 4; ++mt) {
        int e = base + mt * 16 + l15;
        int el = e < E_TOTAL ? e : E_TOTAL - 1;
        pA[mt] = edgef + (size_t)el * ED;
    }

    f32x4 acc1[4][4];
    #pragma unroll
    for (int mt = 0; mt < 4; ++mt)
        #pragma unroll
        for (int nt = 0; nt < 4; ++nt)
            acc1[mt][nt] = (f32x4)0.0f;

    #pragma unroll
    for (int ks = 0; ks < 4; ++ks) {
        int c0 = ks * 32 + lhi * 8;
        bf16x8 a[4];
        #pragma unroll
        for (int mt = 0; mt < 4; ++mt) {
            float4 f0 = *(const float4*)(pA[mt] + c0);
            float4 f1 = *(const float4*)(pA[mt] + c0 + 4);
            a[mt][0] = (short)f2bf(f0.x); a[mt][1] = (short)f2bf(f0.y);
            a[mt][2] = (short)f2bf(f0.z); a[mt][3] = (short)f2bf(f0.w);
            a[mt][4] = (short)f2bf(f1.x); a[mt][5] = (short)f2bf(f1.y);
            a[mt][6] = (short)f2bf(f1.z); a[mt][7] = (short)f2bf(f1.w);
        }
        #pragma unroll
        for (int nt = 0; nt < 4; ++nt) {
            int n = w * 64 + nt * 16 + l15;
            bf16x8 b = *(const bf16x8*)(w1t + (size_t)n * IND + 256 + c0);
            #pragma unroll
            for (int mt = 0; mt < 4; ++mt)
                acc1[mt][nt] = __builtin_amdgcn_mfma_f32_16x16x32_bf16(a[mt], b, acc1[mt][nt], 0, 0, 0);
        }
    }
    __syncthreads();   // all gather writes visible

    // ---- merge: Hs = relu(acc1 + Hs) in place (b1 folded in Psrc) ----
    #pragma unroll
    for (int nt = 0; nt < 4; ++nt) {
        int col = w * 64 + nt * 16 + l15;
        #pragma unroll
        for (int mt = 0; mt < 4; ++mt) {
            #pragma unroll
            for (int r = 0; r < 4; ++r) {
                int row = mt * 16 + lhi * 4 + r;
                int idx = row * HID + (col ^ ((row & 7) * 8));
                float v = acc1[mt][nt][r] + bf2f(Hs[idx]);
                v = v > 0.0f ? v : 0.0f;
                Hs[idx] = f2bf(v);
            }
        }
    }
    __syncthreads();

    // ---- GEMM2: U(64x128) = Hs(64x256) @ W2 ----
    f32x4 acc2[4][2];
    #pragma unroll
    for (int mt = 0; mt < 4; ++mt)
        #pragma unroll
        for (int nt = 0; nt < 2; ++nt)
            acc2[mt][nt] = (f32x4)0.0f;

    #pragma unroll
    for (int ks = 0; ks < 8; ++ks) {
        int c0 = ks * 32 + lhi * 8;
        bf16x8 a[4];
        #pragma unroll
        for (int mt = 0; mt < 4; ++mt) {
            int row = mt * 16 + l15;
            a[mt] = *(const bf16x8*)(Hs + row * HID + (c0 ^ ((row & 7) * 8)));
        }
        #pragma unroll
        for (int nt = 0; nt < 2; ++nt) {
            int n = w * 32 + nt * 16 + l15;
            bf16x8 b = *(const bf16x8*)(w2t + (size_t)n * HID + c0);
            #pragma unroll
            for (int mt = 0; mt < 4; ++mt)
                acc2[mt][nt] = __builtin_amdgcn_mfma_f32_16x16x32_bf16(a[mt], b, acc2[mt][nt], 0, 0, 0);
        }
    }

    // ---- epilogue: out = edgef(f32, L2-hot) + update + b2 ----
    #pragma unroll
    for (int nt = 0; nt < 2; ++nt) {
        int col = w * 32 + nt * 16 + l15;
        float bias = b2[col];
        #pragma unroll
        for (int mt = 0; mt < 4; ++mt) {
            #pragma unroll
            for (int r = 0; r < 4; ++r) {
                int row = mt * 16 + lhi * 4 + r;
                int e = base + row;
                if (e < E_TOTAL) {
                    size_t off = (size_t)e * ED + col;
                    out[off] = edgef[off] + acc2[mt][nt][r] + bias;
                }
            }
        }
    }
}

extern "C" void kernel_launch(void* const* d_in, const int* in_sizes, int n_in,
                              void* d_out, int out_size, void* d_ws, size_t ws_size,
                              hipStream_t stream) {
    const float* nf   = (const float*)d_in[0];
    const float* ef   = (const float*)d_in[1];
    const int*   eidx = (const int*)d_in[2];
    const float* W1   = (const float*)d_in[3];
    const float* b1   = (const float*)d_in[4];
    const float* W2   = (const float*)d_in[5];
    const float* b2   = (const float*)d_in[6];
    float* out = (float*)d_out;

    unsigned short* w1t  = (unsigned short*)d_ws;          // 192 KB
    unsigned short* w2t  = w1t + IND * HID;                // 64 KB
    unsigned short* Psrc = w2t + HID * ED;                 // 25.6 MB
    unsigned short* Pdst = Psrc + (size_t)NN * HID;        // 25.6 MB

    prep_w1<<<(IND * HID + 255) / 256, 256, 0, stream>>>(W1, w1t);
    prep_w2<<<(HID * ED + 255) / 256, 256, 0, stream>>>(W2, w2t);
    prep_ptab<<<(NN + EB - 1) / EB, 256, 0, stream>>>(nf, w1t, b1, Psrc, Pdst);
    edge_mlp<<<NBLOCKS, 256, 0, stream>>>(ef, eidx, Psrc, Pdst, w1t, w2t, b2, out);
}

// Round 6
// 603.853 us; speedup vs baseline: 1.1258x; 1.1258x over previous
//
#include <hip/hip_runtime.h>

#define E_TOTAL   500000
#define NN        50000
#define ND        128
#define ED        128
#define HID       256
#define IND       384   /* 2*ND + ED */
#define WEB       16    /* edges per wave */
#define BEB       128   /* edges per block (8 waves) */
#define NBLOCKS   ((E_TOTAL + BEB - 1) / BEB)

typedef float  f32x4  __attribute__((ext_vector_type(4)));
typedef short  bf16x8 __attribute__((ext_vector_type(8)));

__device__ __forceinline__ unsigned short f2bf(float f) {
    unsigned int u = __float_as_uint(f);
    u += 0x7FFFu + ((u >> 16) & 1u);   // RNE
    return (unsigned short)(u >> 16);
}
__device__ __forceinline__ float bf2f(unsigned short h) {
    return __uint_as_float(((unsigned int)h) << 16);
}

// ---------------- prep: both weights fp32 -> bf16 transposed ----------------
__global__ void prep_weights(const float* __restrict__ w1, const float* __restrict__ w2,
                             unsigned short* __restrict__ w1t, unsigned short* __restrict__ w2t) {
    int i = blockIdx.x * blockDim.x + threadIdx.x;
    if (i < IND * HID) {
        int k = i / HID, n = i % HID;
        w1t[n * IND + k] = f2bf(w1[i]);          // W1T[n][k] = W1[k][n]
    } else if (i < IND * HID + HID * ED) {
        int q = i - IND * HID;
        int k = q / ED, n = q % ED;
        w2t[n * HID + k] = f2bf(w2[q]);          // W2T[n][k] = W2[k][n]
    }
}

// ---------------- prep: per-node partial products ----------------
// Psrc[n][:] = nodes[n] @ W1[0:128, :] + b1   (bf16, 50000x256)
// Pdst[n][:] = nodes[n] @ W1[128:256, :]      (bf16, 50000x256)
__global__ __launch_bounds__(256, 2)
void prep_ptab(const float* __restrict__ nf,
               const unsigned short* __restrict__ w1t,
               const float* __restrict__ b1,
               unsigned short* __restrict__ Psrc,
               unsigned short* __restrict__ Pdst) {
    __shared__ unsigned short An[64 * ND];   // 16 KB swizzled
    const int tid  = threadIdx.x;
    const int base = blockIdx.x * 64;
    const int lane = tid & 63;
    const int w    = tid >> 6;
    const int l15  = lane & 15;
    const int lhi  = lane >> 4;

    #pragma unroll
    for (int it = 0; it < 4; ++it) {
        int item = tid + it * 256;          // 0..1023
        int row = item >> 4, cc = item & 15;
        int nidx = base + row;
        if (nidx >= NN) nidx = NN - 1;
        const float* p = nf + (size_t)nidx * ND + cc * 8;
        float4 f0 = *(const float4*)p;
        float4 f1 = *(const float4*)(p + 4);
        bf16x8 val;
        val[0] = (short)f2bf(f0.x); val[1] = (short)f2bf(f0.y);
        val[2] = (short)f2bf(f0.z); val[3] = (short)f2bf(f0.w);
        val[4] = (short)f2bf(f1.x); val[5] = (short)f2bf(f1.y);
        val[6] = (short)f2bf(f1.z); val[7] = (short)f2bf(f1.w);
        *(bf16x8*)(An + row * ND + ((cc * 8) ^ ((row & 7) * 8))) = val;
    }
    __syncthreads();

    f32x4 accs[4][4], accd[4][4];
    #pragma unroll
    for (int mt = 0; mt < 4; ++mt)
        #pragma unroll
        for (int nt = 0; nt < 4; ++nt) { accs[mt][nt] = (f32x4)0.0f; accd[mt][nt] = (f32x4)0.0f; }

    #pragma unroll
    for (int ks = 0; ks < 4; ++ks) {
        int c0 = ks * 32 + lhi * 8;
        bf16x8 a[4];
        #pragma unroll
        for (int mt = 0; mt < 4; ++mt) {
            int row = mt * 16 + l15;
            a[mt] = *(const bf16x8*)(An + row * ND + (c0 ^ ((row & 7) * 8)));
        }
        #pragma unroll
        for (int nt = 0; nt < 4; ++nt) {
            int n = w * 64 + nt * 16 + l15;
            bf16x8 bs = *(const bf16x8*)(w1t + (size_t)n * IND + c0);
            bf16x8 bd = *(const bf16x8*)(w1t + (size_t)n * IND + 128 + c0);
            #pragma unroll
            for (int mt = 0; mt < 4; ++mt) {
                accs[mt][nt] = __builtin_amdgcn_mfma_f32_16x16x32_bf16(a[mt], bs, accs[mt][nt], 0, 0, 0);
                accd[mt][nt] = __builtin_amdgcn_mfma_f32_16x16x32_bf16(a[mt], bd, accd[mt][nt], 0, 0, 0);
            }
        }
    }

    #pragma unroll
    for (int nt = 0; nt < 4; ++nt) {
        int col = w * 64 + nt * 16 + l15;
        float bias = b1[col];
        #pragma unroll
        for (int mt = 0; mt < 4; ++mt) {
            #pragma unroll
            for (int r = 0; r < 4; ++r) {
                int row = mt * 16 + lhi * 4 + r;
                int nidx = base + row;
                if (nidx < NN) {
                    size_t off = (size_t)nidx * HID + col;
                    Psrc[off] = f2bf(accs[mt][nt][r] + bias);
                    Pdst[off] = f2bf(accd[mt][nt][r]);
                }
            }
        }
    }
}

// ---------------- main fused kernel: wave-private, ZERO barriers ----------------
// Each wave owns 16 edges end-to-end. Per-wave LDS slice (8 KB) serves as:
//   (1) Hs[16][256] bf16: gathered Psrc+Pdst, merged in place with GEMM1+relu
//   (2) after GEMM2: reinterpreted as U[16][128] f32 for the coalesced epilogue
// No __syncthreads(): every wave is an independent latency chain.
__global__ __launch_bounds__(512, 4)
void edge_mlp(const float* __restrict__ edgef,
              const int* __restrict__ eidx,
              const unsigned short* __restrict__ Psrc,
              const unsigned short* __restrict__ Pdst,
              const unsigned short* __restrict__ w1t,
              const unsigned short* __restrict__ w2t,
              const float* __restrict__ b2,
              float* __restrict__ out) {
    __shared__ __align__(16) unsigned short HsAll[8 * WEB * HID];   // 64 KB
    unsigned short* Hs  = HsAll + (threadIdx.x >> 6) * (WEB * HID);
    float*          HsF = (float*)Hs;                               // f32 view (U bounce)

    const int lane  = threadIdx.x & 63;
    const int w     = threadIdx.x >> 6;
    const int l15   = lane & 15;
    const int lhi   = lane >> 4;     // 0..3
    const int l4    = lane & 3;      // 0..3
    const int lr    = lane >> 2;     // 0..15 (row for gather/epilogue)
    const int ebase = blockIdx.x * BEB + w * WEB;
    const int* srcI = eidx;
    const int* dstI = eidx + E_TOTAL;

    // ---- gather: Hs[row] = Psrc[src[row]] + Pdst[dst[row]]  (4 lanes/row) ----
    int erow = ebase + lr;
    int erc  = erow < E_TOTAL ? erow : E_TOTAL - 1;
    int sg = srcI[erc], dg = dstI[erc];
    const unsigned short* ps = Psrc + (size_t)sg * HID;
    const unsigned short* pd = Pdst + (size_t)dg * HID;
    #pragma unroll
    for (int j = 0; j < 8; ++j) {
        int c = l4 + 4 * j;              // 16B chunk 0..31
        bf16x8 vs = *(const bf16x8*)(ps + c * 8);
        bf16x8 vd = *(const bf16x8*)(pd + c * 8);
        bf16x8 o;
        #pragma unroll
        for (int jj = 0; jj < 8; ++jj)
            o[jj] = (short)f2bf(bf2f((unsigned short)vs[jj]) + bf2f((unsigned short)vd[jj]));
        *(bf16x8*)(Hs + lr * HID + ((c * 8) ^ ((lr & 7) * 8))) = o;
    }

    // ---- GEMM1 A-fragments direct from edgef (wave-private rows, read once) ----
    int ea  = ebase + l15;
    int eac = ea < E_TOTAL ? ea : E_TOTAL - 1;
    const float* pA = edgef + (size_t)eac * ED;
    bf16x8 a1[4];
    #pragma unroll
    for (int ks = 0; ks < 4; ++ks) {
        int c0 = ks * 32 + lhi * 8;
        float4 f0 = *(const float4*)(pA + c0);
        float4 f1 = *(const float4*)(pA + c0 + 4);
        a1[ks][0] = (short)f2bf(f0.x); a1[ks][1] = (short)f2bf(f0.y);
        a1[ks][2] = (short)f2bf(f0.z); a1[ks][3] = (short)f2bf(f0.w);
        a1[ks][4] = (short)f2bf(f1.x); a1[ks][5] = (short)f2bf(f1.y);
        a1[ks][6] = (short)f2bf(f1.z); a1[ks][7] = (short)f2bf(f1.w);
    }

    // ---- GEMM1: acc1(16x256) = edge(16x128) @ W1[256:384,:] ----
    f32x4 acc1[16];
    #pragma unroll
    for (int nt = 0; nt < 16; ++nt) acc1[nt] = (f32x4)0.0f;
    #pragma unroll
    for (int nt = 0; nt < 16; ++nt) {
        int n = nt * 16 + l15;
        #pragma unroll
        for (int ks = 0; ks < 4; ++ks) {
            bf16x8 b = *(const bf16x8*)(w1t + (size_t)n * IND + 256 + ks * 32 + lhi * 8);
            acc1[nt] = __builtin_amdgcn_mfma_f32_16x16x32_bf16(a1[ks], b, acc1[nt], 0, 0, 0);
        }
    }

    // ---- merge: Hs = relu(acc1 + Hs) in place (b1 folded in Psrc) ----
    // wave-private LDS; DS ops execute in order within a wave, no barrier
    #pragma unroll
    for (int nt = 0; nt < 16; ++nt) {
        int col = nt * 16 + l15;
        #pragma unroll
        for (int r = 0; r < 4; ++r) {
            int row = lhi * 4 + r;
            int idx = row * HID + (col ^ ((row & 7) * 8));
            float v = acc1[nt][r] + bf2f(Hs[idx]);
            v = v > 0.0f ? v : 0.0f;
            Hs[idx] = f2bf(v);
        }
    }

    // ---- GEMM2 A-fragments (read all of H before U overwrites the slice) ----
    bf16x8 a2[8];
    #pragma unroll
    for (int ks = 0; ks < 8; ++ks) {
        int c0 = ks * 32 + lhi * 8;
        a2[ks] = *(const bf16x8*)(Hs + l15 * HID + (c0 ^ ((l15 & 7) * 8)));
    }
    asm volatile("" ::: "memory");   // fence: a2 reads stay above U f32 writes

    // ---- GEMM2: acc2(16x128) = H(16x256) @ W2 ----
    f32x4 acc2[8];
    #pragma unroll
    for (int nt = 0; nt < 8; ++nt) acc2[nt] = (f32x4)0.0f;
    #pragma unroll
    for (int nt = 0; nt < 8; ++nt) {
        int n = nt * 16 + l15;
        #pragma unroll
        for (int ks = 0; ks < 8; ++ks) {
            bf16x8 b = *(const bf16x8*)(w2t + (size_t)n * HID + ks * 32 + lhi * 8);
            acc2[nt] = __builtin_amdgcn_mfma_f32_16x16x32_bf16(a2[ks], b, acc2[nt], 0, 0, 0);
        }
    }

    // ---- U bounce: HsF[16][128] f32, swizzle ^(4*(row&7)) (float4-safe) ----
    #pragma unroll
    for (int nt = 0; nt < 8; ++nt) {
        int col = nt * 16 + l15;
        #pragma unroll
        for (int r = 0; r < 4; ++r) {
            int row = lhi * 4 + r;
            HsF[row * ED + (col ^ ((row & 7) * 4))] = acc2[nt][r];
        }
    }
    asm volatile("" ::: "memory");

    // ---- epilogue: fully-coalesced float4 rows: out = edgef + U + b2 ----
    const float* pE = edgef + (size_t)erc * ED;
    float*       pO = out   + (size_t)erc * ED;
    bool valid = erow < E_TOTAL;
    #pragma unroll
    for (int j = 0; j < 8; ++j) {
        int c  = l4 + 4 * j;                       // float4 chunk 0..31
        int e0 = (c * 4) ^ ((lr & 7) * 4);         // swizzled f32 elem (4-aligned)
        float4 u  = *(const float4*)(HsF + lr * ED + e0);
        float4 eg = *(const float4*)(pE + c * 4);
        float4 bb = *(const float4*)(b2 + c * 4);
        float4 o;
        o.x = eg.x + u.x + bb.x;
        o.y = eg.y + u.y + bb.y;
        o.z = eg.z + u.z + bb.z;
        o.w = eg.w + u.w + bb.w;
        if (valid) *(float4*)(pO + c * 4) = o;
    }
}

extern "C" void kernel_launch(void* const* d_in, const int* in_sizes, int n_in,
                              void* d_out, int out_size, void* d_ws, size_t ws_size,
                              hipStream_t stream) {
    const float* nf   = (const float*)d_in[0];
    const float* ef   = (const float*)d_in[1];
    const int*   eidx = (const int*)d_in[2];
    const float* W1   = (const float*)d_in[3];
    const float* b1   = (const float*)d_in[4];
    const float* W2   = (const float*)d_in[5];
    const float* b2   = (const float*)d_in[6];
    float* out = (float*)d_out;

    unsigned short* w1t  = (unsigned short*)d_ws;          // 192 KB
    unsigned short* w2t  = w1t + IND * HID;                // 64 KB
    unsigned short* Psrc = w2t + HID * ED;                 // 25.6 MB
    unsigned short* Pdst = Psrc + (size_t)NN * HID;        // 25.6 MB

    int wtotal = IND * HID + HID * ED;
    prep_weights<<<(wtotal + 255) / 256, 256, 0, stream>>>(W1, W2, w1t, w2t);
    prep_ptab<<<(NN + 63) / 64, 256, 0, stream>>>(nf, w1t, b1, Psrc, Pdst);
    edge_mlp<<<NBLOCKS, 512, 0, stream>>>(ef, eidx, Psrc, Pdst, w1t, w2t, b2, out);
}

// Round 7
// 326.181 us; speedup vs baseline: 2.0842x; 1.8513x over previous
//
#include <hip/hip_runtime.h>

#define E_TOTAL   500000
#define NN        50000
#define ND        128
#define ED        128
#define HID       256
#define IND       384   /* 2*ND + ED */
#define EB        64    /* edges per block */
#define NBLOCKS   ((E_TOTAL + EB - 1) / EB)

typedef float  f32x4  __attribute__((ext_vector_type(4)));
typedef short  bf16x8 __attribute__((ext_vector_type(8)));

__device__ __forceinline__ unsigned short f2bf(float f) {
    unsigned int u = __float_as_uint(f);
    u += 0x7FFFu + ((u >> 16) & 1u);   // RNE
    return (unsigned short)(u >> 16);
}
__device__ __forceinline__ float bf2f(unsigned short h) {
    return __uint_as_float(((unsigned int)h) << 16);
}

// ---------------- prep: both weights fp32 -> bf16 transposed ----------------
__global__ void prep_weights(const float* __restrict__ w1, const float* __restrict__ w2,
                             unsigned short* __restrict__ w1t, unsigned short* __restrict__ w2t) {
    int i = blockIdx.x * blockDim.x + threadIdx.x;
    if (i < IND * HID) {
        int k = i / HID, n = i % HID;
        w1t[n * IND + k] = f2bf(w1[i]);          // W1T[n][k] = W1[k][n]
    } else if (i < IND * HID + HID * ED) {
        int q = i - IND * HID;
        int k = q / ED, n = q % ED;
        w2t[n * HID + k] = f2bf(w2[q]);          // W2T[n][k] = W2[k][n]
    }
}

// ---------------- prep: per-node partial products ----------------
// Psrc[n][:] = nodes[n] @ W1[0:128, :] + b1   (bf16, 50000x256)
// Pdst[n][:] = nodes[n] @ W1[128:256, :]      (bf16, 50000x256)
__global__ __launch_bounds__(256, 2)
void prep_ptab(const float* __restrict__ nf,
               const unsigned short* __restrict__ w1t,
               const float* __restrict__ b1,
               unsigned short* __restrict__ Psrc,
               unsigned short* __restrict__ Pdst) {
    __shared__ unsigned short An[64 * ND];   // 16 KB swizzled
    const int tid  = threadIdx.x;
    const int base = blockIdx.x * 64;
    const int lane = tid & 63;
    const int w    = tid >> 6;
    const int l15  = lane & 15;
    const int lhi  = lane >> 4;

    #pragma unroll
    for (int it = 0; it < 4; ++it) {
        int item = tid + it * 256;          // 0..1023
        int row = item >> 4, cc = item & 15;
        int nidx = base + row;
        if (nidx >= NN) nidx = NN - 1;
        const float* p = nf + (size_t)nidx * ND + cc * 8;
        float4 f0 = *(const float4*)p;
        float4 f1 = *(const float4*)(p + 4);
        bf16x8 val;
        val[0] = (short)f2bf(f0.x); val[1] = (short)f2bf(f0.y);
        val[2] = (short)f2bf(f0.z); val[3] = (short)f2bf(f0.w);
        val[4] = (short)f2bf(f1.x); val[5] = (short)f2bf(f1.y);
        val[6] = (short)f2bf(f1.z); val[7] = (short)f2bf(f1.w);
        *(bf16x8*)(An + row * ND + ((cc * 8) ^ ((row & 7) * 8))) = val;
    }
    __syncthreads();

    f32x4 accs[4][4], accd[4][4];
    #pragma unroll
    for (int mt = 0; mt < 4; ++mt)
        #pragma unroll
        for (int nt = 0; nt < 4; ++nt) { accs[mt][nt] = (f32x4)0.0f; accd[mt][nt] = (f32x4)0.0f; }

    #pragma unroll
    for (int ks = 0; ks < 4; ++ks) {
        int c0 = ks * 32 + lhi * 8;
        bf16x8 a[4];
        #pragma unroll
        for (int mt = 0; mt < 4; ++mt) {
            int row = mt * 16 + l15;
            a[mt] = *(const bf16x8*)(An + row * ND + (c0 ^ ((row & 7) * 8)));
        }
        #pragma unroll
        for (int nt = 0; nt < 4; ++nt) {
            int n = w * 64 + nt * 16 + l15;
            bf16x8 bs = *(const bf16x8*)(w1t + (size_t)n * IND + c0);
            bf16x8 bd = *(const bf16x8*)(w1t + (size_t)n * IND + 128 + c0);
            #pragma unroll
            for (int mt = 0; mt < 4; ++mt) {
                accs[mt][nt] = __builtin_amdgcn_mfma_f32_16x16x32_bf16(a[mt], bs, accs[mt][nt], 0, 0, 0);
                accd[mt][nt] = __builtin_amdgcn_mfma_f32_16x16x32_bf16(a[mt], bd, accd[mt][nt], 0, 0, 0);
            }
        }
    }

    #pragma unroll
    for (int nt = 0; nt < 4; ++nt) {
        int col = w * 64 + nt * 16 + l15;
        float bias = b1[col];
        #pragma unroll
        for (int mt = 0; mt < 4; ++mt) {
            #pragma unroll
            for (int r = 0; r < 4; ++r) {
                int row = mt * 16 + lhi * 4 + r;
                int nidx = base + row;
                if (nidx < NN) {
                    size_t off = (size_t)nidx * HID + col;
                    Psrc[off] = f2bf(accs[mt][nt][r] + bias);
                    Pdst[off] = f2bf(accd[mt][nt][r]);
                }
            }
        }
    }
}

// ---------------- main fused kernel: R3 skeleton, 8 waves/block ----------------
// 64-edge tile, 512 threads (8 waves). LDS: Ae 16KB + Hs 32KB = 48KB ->
// 3 blocks/CU = 24 waves/CU. N-split GEMMs: wave w owns 32 cols of GEMM1,
// 16 cols of GEMM2 (B-traffic per block unchanged; A shared via LDS).
__global__ __launch_bounds__(512, 6)
void edge_mlp(const float* __restrict__ edgef,
              const int* __restrict__ eidx,
              const unsigned short* __restrict__ Psrc,
              const unsigned short* __restrict__ Pdst,
              const unsigned short* __restrict__ w1t,
              const unsigned short* __restrict__ w2t,
              const float* __restrict__ b2,
              float* __restrict__ out) {
    __shared__ unsigned short Ae[EB * ND];    // 16 KB
    __shared__ unsigned short Hs[EB * HID];   // 32 KB

    const int tid  = threadIdx.x;
    const int base = blockIdx.x * EB;
    const int lane = tid & 63;
    const int w    = tid >> 6;       // 0..7
    const int l15  = lane & 15;
    const int lhi  = lane >> 4;
    const int* srcI = eidx;
    const int* dstI = eidx + E_TOTAL;

    // ---- gather: Hs[row][:] = Psrc[src[row]][:] + Pdst[dst[row]][:] ----
    #pragma unroll
    for (int it = 0; it < 4; ++it) {
        int item = tid + it * 512;           // 0..2047 = 64 rows x 32 chunks
        int row = item >> 5, cc = item & 31;
        int e = base + row;
        int el = e < E_TOTAL ? e : E_TOTAL - 1;
        int s = srcI[el], d = dstI[el];
        bf16x8 vs = *(const bf16x8*)(Psrc + (size_t)s * HID + cc * 8);
        bf16x8 vd = *(const bf16x8*)(Pdst + (size_t)d * HID + cc * 8);
        bf16x8 o;
        #pragma unroll
        for (int j = 0; j < 8; ++j)
            o[j] = (short)f2bf(bf2f((unsigned short)vs[j]) + bf2f((unsigned short)vd[j]));
        *(bf16x8*)(Hs + row * HID + ((cc * 8) ^ ((row & 7) * 8))) = o;
    }

    // ---- stage Ae: 64x128 edge features f32 -> bf16 (coalesced, read ONCE) ----
    #pragma unroll
    for (int it = 0; it < 2; ++it) {
        int item = tid + it * 512;           // 0..1023 = 64 rows x 16 chunks
        int row = item >> 4, cc = item & 15;
        int e = base + row;
        int el = e < E_TOTAL ? e : E_TOTAL - 1;
        const float* p = edgef + (size_t)el * ED + cc * 8;
        float4 f0 = *(const float4*)p;
        float4 f1 = *(const float4*)(p + 4);
        bf16x8 val;
        val[0] = (short)f2bf(f0.x); val[1] = (short)f2bf(f0.y);
        val[2] = (short)f2bf(f0.z); val[3] = (short)f2bf(f0.w);
        val[4] = (short)f2bf(f1.x); val[5] = (short)f2bf(f1.y);
        val[6] = (short)f2bf(f1.z); val[7] = (short)f2bf(f1.w);
        *(bf16x8*)(Ae + row * ND + ((cc * 8) ^ ((row & 7) * 8))) = val;
    }
    __syncthreads();

    // ---- GEMM1: acc1(64x32 slice) = Ae(64x128) @ W1[256:384, w*32..] ----
    f32x4 acc1[4][2];
    #pragma unroll
    for (int mt = 0; mt < 4; ++mt)
        #pragma unroll
        for (int nt = 0; nt < 2; ++nt)
            acc1[mt][nt] = (f32x4)0.0f;

    #pragma unroll
    for (int ks = 0; ks < 4; ++ks) {
        int c0 = ks * 32 + lhi * 8;
        bf16x8 a[4];
        #pragma unroll
        for (int mt = 0; mt < 4; ++mt) {
            int row = mt * 16 + l15;
            a[mt] = *(const bf16x8*)(Ae + row * ND + (c0 ^ ((row & 7) * 8)));
        }
        #pragma unroll
        for (int nt = 0; nt < 2; ++nt) {
            int n = w * 32 + nt * 16 + l15;
            bf16x8 b = *(const bf16x8*)(w1t + (size_t)n * IND + 256 + c0);
            #pragma unroll
            for (int mt = 0; mt < 4; ++mt)
                acc1[mt][nt] = __builtin_amdgcn_mfma_f32_16x16x32_bf16(a[mt], b, acc1[mt][nt], 0, 0, 0);
        }
    }

    // ---- merge: Hs = relu(acc1 + Hs) in place; per-wave col-slices disjoint ----
    #pragma unroll
    for (int nt = 0; nt < 2; ++nt) {
        int col = w * 32 + nt * 16 + l15;
        #pragma unroll
        for (int mt = 0; mt < 4; ++mt) {
            #pragma unroll
            for (int r = 0; r < 4; ++r) {
                int row = mt * 16 + lhi * 4 + r;
                int idx = row * HID + (col ^ ((row & 7) * 8));
                float v = acc1[mt][nt][r] + bf2f(Hs[idx]);
                v = v > 0.0f ? v : 0.0f;
                Hs[idx] = f2bf(v);
            }
        }
    }
    __syncthreads();

    // ---- GEMM2: acc2(64x16 slice) = Hs(64x256) @ W2[:, w*16..] ----
    f32x4 acc2[4];
    #pragma unroll
    for (int mt = 0; mt < 4; ++mt) acc2[mt] = (f32x4)0.0f;

    #pragma unroll
    for (int ks = 0; ks < 8; ++ks) {
        int c0 = ks * 32 + lhi * 8;
        bf16x8 a[4];
        #pragma unroll
        for (int mt = 0; mt < 4; ++mt) {
            int row = mt * 16 + l15;
            a[mt] = *(const bf16x8*)(Hs + row * HID + (c0 ^ ((row & 7) * 8)));
        }
        int n = w * 16 + l15;
        bf16x8 b = *(const bf16x8*)(w2t + (size_t)n * HID + c0);
        #pragma unroll
        for (int mt = 0; mt < 4; ++mt)
            acc2[mt] = __builtin_amdgcn_mfma_f32_16x16x32_bf16(a[mt], b, acc2[mt], 0, 0, 0);
    }

    // ---- epilogue: out = Ae(bf16 edge) + update + b2 ----
    {
        int col = w * 16 + l15;
        float bias = b2[col];
        #pragma unroll
        for (int mt = 0; mt < 4; ++mt) {
            #pragma unroll
            for (int r = 0; r < 4; ++r) {
                int row = mt * 16 + lhi * 4 + r;
                int e = base + row;
                if (e < E_TOTAL) {
                    float ev = bf2f(Ae[row * ND + (col ^ ((row & 7) * 8))]);
                    out[(size_t)e * ED + col] = ev + acc2[mt][r] + bias;
                }
            }
        }
    }
}

extern "C" void kernel_launch(void* const* d_in, const int* in_sizes, int n_in,
                              void* d_out, int out_size, void* d_ws, size_t ws_size,
                              hipStream_t stream) {
    const float* nf   = (const float*)d_in[0];
    const float* ef   = (const float*)d_in[1];
    const int*   eidx = (const int*)d_in[2];
    const float* W1   = (const float*)d_in[3];
    const float* b1   = (const float*)d_in[4];
    const float* W2   = (const float*)d_in[5];
    const float* b2   = (const float*)d_in[6];
    float* out = (float*)d_out;

    unsigned short* w1t  = (unsigned short*)d_ws;          // 192 KB
    unsigned short* w2t  = w1t + IND * HID;                // 64 KB
    unsigned short* Psrc = w2t + HID * ED;                 // 25.6 MB
    unsigned short* Pdst = Psrc + (size_t)NN * HID;        // 25.6 MB

    int wtotal = IND * HID + HID * ED;
    prep_weights<<<(wtotal + 255) / 256, 256, 0, stream>>>(W1, W2, w1t, w2t);
    prep_ptab<<<(NN + 63) / 64, 256, 0, stream>>>(nf, w1t, b1, Psrc, Pdst);
    edge_mlp<<<NBLOCKS, 512, 0, stream>>>(ef, eidx, Psrc, Pdst, w1t, w2t, b2, out);
}